// Round 10
// baseline (90.719 us; speedup 1.0000x reference)
//
#include <hip/hip_runtime.h>
#include <hip/hip_bf16.h>

typedef __attribute__((ext_vector_type(8)))  short bf16x8;
typedef __attribute__((ext_vector_type(16))) float f32x16;
typedef __attribute__((ext_vector_type(4)))  float f32x4;
typedef __attribute__((ext_vector_type(2)))  unsigned int u32x2;
typedef __attribute__((ext_vector_type(4)))  unsigned int u32x4;

#define NN 4096
#define CH 256
#define CQ 32

union UB { u32x4 u; bf16x8 h; };

static __device__ __forceinline__ ushort f2bf(float f) {
    __hip_bfloat16 h = __float2bfloat16(f);
    return *reinterpret_cast<ushort*>(&h);
}
static __device__ __forceinline__ uint pack2bf(float a, float b) {
    return (uint)f2bf(a) | ((uint)f2bf(b) << 16);
}
// single-instruction bf16 pair pack (T12)
static __device__ __forceinline__ uint cvt_pk_bf16(float a, float b) {
    uint r;
    asm("v_cvt_pk_bf16_f32 %0, %1, %2" : "=v"(r) : "v"(a), "v"(b));
    return r;
}
static __device__ __forceinline__ int swz(int n) {   // 3-bit 16B-slot swizzle
    return ((n & 7) ^ ((n >> 3) & 7)) << 4;
}
// async global->LDS DMA, 16B per lane: lane i's 16B lands at ldst + i*16
static __device__ __forceinline__ void gll16(const void* gsrc, void* ldst) {
    __builtin_amdgcn_global_load_lds(
        (const __attribute__((address_space(1))) uint*)gsrc,
        (__attribute__((address_space(3))) uint*)ldst, 16, 0, 0);
}

// ---------------------------------------------------------------------------
// Fragment-tiled workspace layouts (bf16, 32x32 tiles of 1024 ushorts,
// in-tile offset = frag*512u + lane*8u). Frag loads: 64 lanes x 16B = 16 full
// 64B lines, lane-linear (so global_load_lds dest is linear too).
// ---------------------------------------------------------------------------

// Fused Q/K/V projection, bf16 MFMA. grid (32 nblk, 5 chb, 4 b), block 256.
__global__ __launch_bounds__(256) void proj_mfma(
    const float* __restrict__ x,
    const float* __restrict__ Wq, const float* __restrict__ bq,
    const float* __restrict__ Wk, const float* __restrict__ bk,
    const float* __restrict__ Wv, const float* __restrict__ bv,
    ushort* __restrict__ qT, ushort* __restrict__ kT, ushort* __restrict__ v)
{
    const int nblk = blockIdx.x;
    const int chb  = blockIdx.y;
    const int b    = blockIdx.z;
    const int t    = threadIdx.x;
    const int w    = t >> 6;
    const int wc   = w >> 1, wn = w & 1;
    const int lane = t & 63;
    const int l31  = lane & 31;
    const int h5   = lane >> 5;

    __shared__ ushort Wl[64 * 256];     // 32 KB  [ch][c] bf16, 512B rows, swizzled
    __shared__ ushort Xl[128 * 64];     // 16 KB  [n][c]  bf16, 128B rows, swizzled

    // ---- stage W (64 out-ch x 256 c) fp32 -> bf16, once ----
    {
        const int ch  = t >> 2;
        const int c0  = (t & 3) * 64;
        const int chg = chb * 64 + ch;
        const float* wr; float sc = 1.0f;
        if (chg < 256)      wr = Wv + (size_t)chg * CH;
        else if (chg < 288) { wr = Wq + (size_t)(chg - 256) * CH; sc = 1.44269504f; }
        else                wr = Wk + (size_t)(chg - 288) * CH;
        const int sw = swz(ch);
#pragma unroll
        for (int j = 0; j < 16; ++j) {
            const int c = c0 + 4 * j;
            float4 f = *reinterpret_cast<const float4*>(wr + c);
            u32x2 p; p.x = pack2bf(f.x * sc, f.y * sc); p.y = pack2bf(f.z * sc, f.w * sc);
            *reinterpret_cast<u32x2*>((char*)Wl + ((ch * 512 + c * 2) ^ sw)) = p;
        }
    }

    const f32x16 z16 = {0,0,0,0, 0,0,0,0, 0,0,0,0, 0,0,0,0};
    f32x16 acc0 = z16, acc1 = z16;
    const float* xb = x + (size_t)b * CH * NN + nblk * 128;

    for (int cs = 0; cs < 4; ++cs) {
        if (cs) __syncthreads();
#pragma unroll
        for (int half = 0; half < 2; ++half) {
            const int cl0 = half * 32 + 4 * (t >> 5);
            const int nl0 = 4 * (t & 31);
            const float4 r0 = *reinterpret_cast<const float4*>(xb + (size_t)(cs*64 + cl0 + 0) * NN + nl0);
            const float4 r1 = *reinterpret_cast<const float4*>(xb + (size_t)(cs*64 + cl0 + 1) * NN + nl0);
            const float4 r2 = *reinterpret_cast<const float4*>(xb + (size_t)(cs*64 + cl0 + 2) * NN + nl0);
            const float4 r3 = *reinterpret_cast<const float4*>(xb + (size_t)(cs*64 + cl0 + 3) * NN + nl0);
#pragma unroll
            for (int e = 0; e < 4; ++e) {
                const int nl = nl0 + e;
                u32x2 p;
                p.x = pack2bf(((const float*)&r0)[e], ((const float*)&r1)[e]);
                p.y = pack2bf(((const float*)&r2)[e], ((const float*)&r3)[e]);
                *reinterpret_cast<u32x2*>((char*)Xl + ((nl * 128 + cl0 * 2) ^ swz(nl))) = p;
            }
        }
        __syncthreads();
#pragma unroll
        for (int kl = 0; kl < 4; ++kl) {
            const int ks  = cs * 4 + kl;
            const int chl = 32 * wc + l31;
            const bf16x8 af = *reinterpret_cast<const bf16x8*>(
                (char*)Wl + ((chl * 512 + ks * 32 + h5 * 16) ^ swz(chl)));
            {
                const int nl = 64 * wn + l31;
                const bf16x8 bfv = *reinterpret_cast<const bf16x8*>(
                    (char*)Xl + ((nl * 128 + kl * 32 + h5 * 16) ^ swz(nl)));
                acc0 = __builtin_amdgcn_mfma_f32_32x32x16_bf16(af, bfv, acc0, 0, 0, 0);
            }
            {
                const int nl = 64 * wn + 32 + l31;
                const bf16x8 bfv = *reinterpret_cast<const bf16x8*>(
                    (char*)Xl + ((nl * 128 + kl * 32 + h5 * 16) ^ swz(nl)));
                acc1 = __builtin_amdgcn_mfma_f32_32x32x16_bf16(af, bfv, acc1, 0, 0, 0);
            }
        }
    }

    // ---- epilogue: bias + store in fragment-tiled layouts ----
    const int chbase = chb * 64 + 32 * wc;
    if (chb < 4) {
        ushort* vtb = v + (size_t)b * 8 * 128 * 1024;
#pragma unroll
        for (int nt = 0; nt < 2; ++nt) {
            const f32x16 a = nt ? acc1 : acc0;
            const int key = nblk * 128 + 64 * wn + 32 * nt + l31;
            const size_t kb2 = (size_t)(key >> 5) * 1024
                             + ((key >> 4) & 1) * 512 + ((key >> 3) & 1) * 256 + (key & 7);
#pragma unroll
            for (int r = 0; r < 16; ++r) {
                const int ch = chbase + (r & 3) + 8 * (r >> 2) + 4 * h5;
                vtb[(size_t)(ch >> 5) * 128 * 1024 + kb2 + (ch & 31) * 8] = f2bf(a[r] + bv[ch]);
            }
        }
    } else {
        ushort* dst = (wc == 0 ? qT : kT) + (size_t)b * 128 * 1024;
        const float* bs = (wc == 0 ? bq : bk);
        const float bsc = (wc == 0) ? 1.44269504f : 1.0f;
#pragma unroll
        for (int nt = 0; nt < 2; ++nt) {
            const f32x16 a = nt ? acc1 : acc0;
            const int n = nblk * 128 + 64 * wn + 32 * nt + l31;
            uint* tb = (uint*)(dst + (size_t)(n >> 5) * 1024);
#pragma unroll
            for (int r = 0; r < 16; r += 2) {
                const int row = (r & 3) + 8 * (r >> 2) + 4 * h5;   // even
                tb[((row >> 4) & 1) * 256 + ((row >> 3) & 1) * 128 + (n & 31) * 4 + ((row & 7) >> 1)] =
                    pack2bf(a[r] + bs[row] * bsc, a[r + 1] + bs[row + 1] * bsc);
            }
        }
    }
}

// ---------------------------------------------------------------------------
// Flash attention v9: v7/v8 decomposition (wave (kg,cg) owns keys
// 1024*kg..+1024 x channels 128*cg..+128, P in-register via swapped QK^T +
// cvt_pk + permlane32_swap, 1-deep p pipeline, barrier-free main loop,
// end-of-kernel kg tree-reduction) + V STREAMED VIA global_load_lds DMA into
// a per-wave-private LDS double buffer with counted vmcnt(10) (never 0 in
// loop). In-flight V holds ZERO VGPRs -> loads pipeline despite the 256-reg
// budget. The epilogue cbuf aliases the (dead) stage region.
// ---------------------------------------------------------------------------
__global__ __attribute__((amdgpu_flat_work_group_size(512, 512), amdgpu_waves_per_eu(2, 2)))
void attn_v9(
    const ushort* __restrict__ qT, const ushort* __restrict__ kT,
    const ushort* __restrict__ v, float* __restrict__ out)
{
    const int bid  = blockIdx.x;
    const int xcd  = bid & 7;
    const int b    = xcd >> 1;                       // batch locked to XCD pair
    const int qblk = (bid >> 3) + 32 * (xcd & 1);
    const int i0   = qblk * 64;

    const int t    = threadIdx.x;
    const int w    = t >> 6;
    const int kg   = w >> 1;          // key group 0..3 (1024 keys each)
    const int cg   = w & 1;           // channel half 0..1 (128 ch each)
    const int lane = t & 63;
    const int l31  = lane & 31;
    const int h5   = lane >> 5;
    const int lo8  = lane * 8;        // frag lane offset (ushort units)

    __shared__ alignas(16) char ldsA[131072];   // main loop: 8 waves x 16 KB V dbuf
                                                // epilogue: f32x4 cbuf (aliased)
    __shared__ float red[2][4][32];             // 1 KB denominators [qt][kg][q]

    char* wb = ldsA + w * 16384;      // this wave's stage region

    // wave-uniform bases (lane offset added only at deref)
    const ushort* qTu = qT + (size_t)b * 128 * 1024;
    const ushort* kTu = kT + ((size_t)b * 128 + kg * 32) * 1024;
    const ushort* vfu = v + (((size_t)b * 8 + cg * 4) * 128 + kg * 32) * 1024;

    // Q B-frags (col = query), both halves, contraction 32 in 2 ksteps
    bf16x8 qf[2][2];
#pragma unroll
    for (int qt = 0; qt < 2; ++qt)
#pragma unroll
        for (int ks = 0; ks < 2; ++ks)
            qf[qt][ks] = *reinterpret_cast<const bf16x8*>(
                qTu + (size_t)((i0 >> 5) + qt) * 1024 + ks * 512 + lo8);

    const f32x16 z16 = {0,0,0,0, 0,0,0,0, 0,0,0,0, 0,0,0,0};
    f32x16 acc[4][2];
#pragma unroll
    for (int ct = 0; ct < 4; ++ct) { acc[ct][0] = z16; acc[ct][1] = z16; }
    float ts0 = 0.f, ts1 = 0.f;

    auto expack = [&](const f32x16& s, float& ts, bf16x8& b0, bf16x8& b1) {
        float p[16];
#pragma unroll
        for (int r = 0; r < 16; ++r) p[r] = __builtin_exp2f(s[r]);
        ts += (((p[0]+p[1])+(p[2]+p[3])) + ((p[4]+p[5])+(p[6]+p[7])))
            + (((p[8]+p[9])+(p[10]+p[11])) + ((p[12]+p[13])+(p[14]+p[15])));
        const uint pk0 = cvt_pk_bf16(p[0],  p[1]);
        const uint pk1 = cvt_pk_bf16(p[2],  p[3]);
        const uint pk2 = cvt_pk_bf16(p[4],  p[5]);
        const uint pk3 = cvt_pk_bf16(p[6],  p[7]);
        const uint pk4 = cvt_pk_bf16(p[8],  p[9]);
        const uint pk5 = cvt_pk_bf16(p[10], p[11]);
        const uint pk6 = cvt_pk_bf16(p[12], p[13]);
        const uint pk7 = cvt_pk_bf16(p[14], p[15]);
        const u32x2 s02 = __builtin_amdgcn_permlane32_swap(pk0, pk2, false, false);
        const u32x2 s13 = __builtin_amdgcn_permlane32_swap(pk1, pk3, false, false);
        const u32x2 s46 = __builtin_amdgcn_permlane32_swap(pk4, pk6, false, false);
        const u32x2 s57 = __builtin_amdgcn_permlane32_swap(pk5, pk7, false, false);
        UB u0; u0.u = u32x4{ s02.x, s13.x, s02.y, s13.y };   // keys 8h5..+7   (ks0)
        UB u1; u1.u = u32x4{ s46.x, s57.x, s46.y, s57.y };   // keys 16+8h5..+7 (ks1)
        b0 = u0.h; b1 = u1.h;
    };

    // ---- prologue: stage V(0) via DMA, load K(0), S(0) -> p(0) ----
#pragma unroll
    for (int j = 0; j < 8; ++j)
        gll16(vfu + (size_t)(j >> 1) * 131072 + (j & 1) * 512 + lo8, wb + j * 1024);

    bf16x8 kf0 = *reinterpret_cast<const bf16x8*>(kTu + lo8);
    bf16x8 kf1 = *reinterpret_cast<const bf16x8*>(kTu + 512 + lo8);

    bf16x8 p00, p01, p10, p11;
    {
        f32x16 s0 = __builtin_amdgcn_mfma_f32_32x32x16_bf16(kf0, qf[0][0], z16, 0, 0, 0);
        s0 = __builtin_amdgcn_mfma_f32_32x32x16_bf16(kf1, qf[0][1], s0, 0, 0, 0);
        expack(s0, ts0, p00, p01);
        f32x16 s1 = __builtin_amdgcn_mfma_f32_32x32x16_bf16(kf0, qf[1][0], z16, 0, 0, 0);
        s1 = __builtin_amdgcn_mfma_f32_32x32x16_bf16(kf1, qf[1][1], s1, 0, 0, 0);
        expack(s1, ts1, p10, p11);
    }

#pragma unroll 1
    for (int it = 0; it < 32; ++it) {
        char* cur = wb + (it & 1) * 8192;
        char* nxt = wb + ((it + 1) & 1) * 8192;

        if (it != 31) {
            // ---- issue V(it+1) DMA (8 x 1KB, zero VGPR in flight) ----
            const ushort* vsrc = vfu + (size_t)(it + 1) * 1024;
#pragma unroll
            for (int j = 0; j < 8; ++j)
                gll16(vsrc + (size_t)(j >> 1) * 131072 + (j & 1) * 512 + lo8, nxt + j * 1024);
            // ---- K(it+1) register loads ----
            const ushort* kr = kTu + (size_t)(it + 1) * 1024;
            kf0 = *reinterpret_cast<const bf16x8*>(kr + lo8);
            kf1 = *reinterpret_cast<const bf16x8*>(kr + 512 + lo8);
            // wait: V(it) resident; V(it+1)+K(it+1) (10 ops) stay in flight
            asm volatile("s_waitcnt vmcnt(10)" ::: "memory");
        } else {
            asm volatile("s_waitcnt vmcnt(0)" ::: "memory");
        }
        __builtin_amdgcn_sched_barrier(0);

        // ---- ds_read V(it) frags (lane-linear b128, conflict-free) ----
        bf16x8 vf[8];
#pragma unroll
        for (int j = 0; j < 8; ++j)
            vf[j] = *reinterpret_cast<const bf16x8*>(cur + j * 1024 + lane * 16);

        // ---- PV(it) with p from previous body ----
#pragma unroll
        for (int ct = 0; ct < 4; ++ct) {
            acc[ct][0] = __builtin_amdgcn_mfma_f32_32x32x16_bf16(vf[2*ct],   p00, acc[ct][0], 0, 0, 0);
            acc[ct][0] = __builtin_amdgcn_mfma_f32_32x32x16_bf16(vf[2*ct+1], p01, acc[ct][0], 0, 0, 0);
            acc[ct][1] = __builtin_amdgcn_mfma_f32_32x32x16_bf16(vf[2*ct],   p10, acc[ct][1], 0, 0, 0);
            acc[ct][1] = __builtin_amdgcn_mfma_f32_32x32x16_bf16(vf[2*ct+1], p11, acc[ct][1], 0, 0, 0);
        }

        // ---- S(it+1) + expack -> p (overlaps PV at the scheduler's whim) ----
        if (it != 31) {
            f32x16 s0 = __builtin_amdgcn_mfma_f32_32x32x16_bf16(kf0, qf[0][0], z16, 0, 0, 0);
            s0 = __builtin_amdgcn_mfma_f32_32x32x16_bf16(kf1, qf[0][1], s0, 0, 0, 0);
            expack(s0, ts0, p00, p01);
            f32x16 s1 = __builtin_amdgcn_mfma_f32_32x32x16_bf16(kf0, qf[1][0], z16, 0, 0, 0);
            s1 = __builtin_amdgcn_mfma_f32_32x32x16_bf16(kf1, qf[1][1], s1, 0, 0, 0);
            expack(s1, ts1, p10, p11);
        }
    }

    // ---- denominators: sum key-halves, publish per-kg partials (cg0 only) ----
    ts0 += __shfl_xor(ts0, 32);
    ts1 += __shfl_xor(ts1, 32);
    if (cg == 0 && lane < 32) { red[0][kg][l31] = ts0; red[1][kg][l31] = ts1; }

    // ---- kg tree-reduction of acc through LDS (stage region now dead) ----
    f32x4* cb = reinterpret_cast<f32x4*>(ldsA);   // [pair][cg][ct][qt][rg][lane]
    auto cidx = [&](int pair, int ct, int qt, int rg) {
        return ((((pair * 2 + cg) * 4 + ct) * 2 + qt) * 4 + rg) * 64 + lane;
    };
    auto writeC = [&](int pair) {
#pragma unroll
        for (int ct = 0; ct < 4; ++ct)
#pragma unroll
            for (int qt = 0; qt < 2; ++qt)
#pragma unroll
                for (int rg = 0; rg < 4; ++rg) {
                    f32x4 vv = { acc[ct][qt][4*rg],   acc[ct][qt][4*rg+1],
                                 acc[ct][qt][4*rg+2], acc[ct][qt][4*rg+3] };
                    cb[cidx(pair, ct, qt, rg)] = vv;
                }
    };
    auto addC = [&](int pair) {
#pragma unroll
        for (int ct = 0; ct < 4; ++ct)
#pragma unroll
            for (int qt = 0; qt < 2; ++qt)
#pragma unroll
                for (int rg = 0; rg < 4; ++rg) {
                    const f32x4 vv = cb[cidx(pair, ct, qt, rg)];
                    acc[ct][qt][4*rg]   += vv.x;
                    acc[ct][qt][4*rg+1] += vv.y;
                    acc[ct][qt][4*rg+2] += vv.z;
                    acc[ct][qt][4*rg+3] += vv.w;
                }
    };

    __syncthreads();   // stage buffers dead everywhere before aliasing as cbuf
    if (kg >= 2) writeC(kg - 2);
    __syncthreads();
    if (kg < 2) addC(kg);
    __syncthreads();
    if (kg == 1) writeC(1);
    __syncthreads();
    if (kg == 0) {
        addC(1);
        const float inv0 = 1.0f / (red[0][0][l31] + red[0][1][l31] + red[0][2][l31] + red[0][3][l31]);
        const float inv1 = 1.0f / (red[1][0][l31] + red[1][1][l31] + red[1][2][l31] + red[1][3][l31]);
        float* ob = out + (size_t)b * CH * NN + i0;
#pragma unroll
        for (int ct = 0; ct < 4; ++ct)
#pragma unroll
            for (int qt = 0; qt < 2; ++qt) {
                const float inv = qt ? inv1 : inv0;
#pragma unroll
                for (int r = 0; r < 16; ++r) {
                    const int chl = 128 * cg + 32 * ct + (r & 3) + 8 * (r >> 2) + 4 * h5;
                    ob[(size_t)chl * NN + 32 * qt + l31] = acc[ct][qt][r] * inv;
                }
            }
    }
}

extern "C" void kernel_launch(void* const* d_in, const int* in_sizes, int n_in,
                              void* d_out, int out_size, void* d_ws, size_t ws_size,
                              hipStream_t stream) {
    const float* x  = (const float*)d_in[0];
    const float* Wq = (const float*)d_in[1];
    const float* bq = (const float*)d_in[2];
    const float* Wk = (const float*)d_in[3];
    const float* bk = (const float*)d_in[4];
    const float* Wv = (const float*)d_in[5];
    const float* bv = (const float*)d_in[6];
    float* out = (float*)d_out;

    ushort* ws = (ushort*)d_ws;
    ushort* qTf = ws;                                   // 4*128 tiles * 2KB = 1 MB
    ushort* kTf = qTf + (size_t)4 * 128 * 1024;         // 1 MB
    ushort* vf  = kTf + (size_t)4 * 128 * 1024;         // 4*8*128 tiles * 2KB = 8 MB

    proj_mfma<<<dim3(32, 5, 4), 256, 0, stream>>>(x, Wq, bq, Wk, bk, Wv, bv, qTf, kTf, vf);
    attn_v9<<<dim3(256), 512, 0, stream>>>(qTf, kTf, vf, out);
}

// Round 11
// 85.594 us; speedup vs baseline: 1.0599x; 1.0599x over previous
//
#include <hip/hip_runtime.h>
#include <hip/hip_bf16.h>

typedef __attribute__((ext_vector_type(8)))  short bf16x8;
typedef __attribute__((ext_vector_type(16))) float f32x16;
typedef __attribute__((ext_vector_type(4)))  float f32x4;
typedef __attribute__((ext_vector_type(2)))  unsigned int u32x2;
typedef __attribute__((ext_vector_type(4)))  unsigned int u32x4;

#define NN 4096
#define CH 256
#define CQ 32

union UB { u32x4 u; bf16x8 h; };

static __device__ __forceinline__ ushort f2bf(float f) {
    __hip_bfloat16 h = __float2bfloat16(f);
    return *reinterpret_cast<ushort*>(&h);
}
static __device__ __forceinline__ uint pack2bf(float a, float b) {
    return (uint)f2bf(a) | ((uint)f2bf(b) << 16);
}
// single-instruction bf16 pair pack (T12)
static __device__ __forceinline__ uint cvt_pk_bf16(float a, float b) {
    uint r;
    asm("v_cvt_pk_bf16_f32 %0, %1, %2" : "=v"(r) : "v"(a), "v"(b));
    return r;
}
static __device__ __forceinline__ int swz(int n) {   // 3-bit 16B-slot swizzle
    return ((n & 7) ^ ((n >> 3) & 7)) << 4;
}
// async global->LDS DMA, 16B per lane: lane i's 16B lands at ldst + i*16
static __device__ __forceinline__ void gll16(const void* gsrc, void* ldst) {
    __builtin_amdgcn_global_load_lds(
        (const __attribute__((address_space(1))) uint*)gsrc,
        (__attribute__((address_space(3))) uint*)ldst, 16, 0, 0);
}
// raw LDS byte offset of a generic pointer into __shared__ (aperture low bits)
static __device__ __forceinline__ uint ldsOff(void* p) {
    return (uint)(uintptr_t)(__attribute__((address_space(3))) char*)p;
}

// ---------------------------------------------------------------------------
// Fragment-tiled workspace layouts (bf16, 32x32 tiles of 1024 ushorts,
// in-tile offset = frag*512u + lane*8u). Frag loads: 64 lanes x 16B = 16 full
// 64B lines, lane-linear (so global_load_lds dest is linear too).
// ---------------------------------------------------------------------------

// Fused Q/K/V projection, bf16 MFMA. grid (32 nblk, 5 chb, 4 b), block 256.
__global__ __launch_bounds__(256) void proj_mfma(
    const float* __restrict__ x,
    const float* __restrict__ Wq, const float* __restrict__ bq,
    const float* __restrict__ Wk, const float* __restrict__ bk,
    const float* __restrict__ Wv, const float* __restrict__ bv,
    ushort* __restrict__ qT, ushort* __restrict__ kT, ushort* __restrict__ v)
{
    const int nblk = blockIdx.x;
    const int chb  = blockIdx.y;
    const int b    = blockIdx.z;
    const int t    = threadIdx.x;
    const int w    = t >> 6;
    const int wc   = w >> 1, wn = w & 1;
    const int lane = t & 63;
    const int l31  = lane & 31;
    const int h5   = lane >> 5;

    __shared__ ushort Wl[64 * 256];     // 32 KB  [ch][c] bf16, 512B rows, swizzled
    __shared__ ushort Xl[128 * 64];     // 16 KB  [n][c]  bf16, 128B rows, swizzled

    // ---- stage W (64 out-ch x 256 c) fp32 -> bf16, once ----
    {
        const int ch  = t >> 2;
        const int c0  = (t & 3) * 64;
        const int chg = chb * 64 + ch;
        const float* wr; float sc = 1.0f;
        if (chg < 256)      wr = Wv + (size_t)chg * CH;
        else if (chg < 288) { wr = Wq + (size_t)(chg - 256) * CH; sc = 1.44269504f; }
        else                wr = Wk + (size_t)(chg - 288) * CH;
        const int sw = swz(ch);
#pragma unroll
        for (int j = 0; j < 16; ++j) {
            const int c = c0 + 4 * j;
            float4 f = *reinterpret_cast<const float4*>(wr + c);
            u32x2 p; p.x = pack2bf(f.x * sc, f.y * sc); p.y = pack2bf(f.z * sc, f.w * sc);
            *reinterpret_cast<u32x2*>((char*)Wl + ((ch * 512 + c * 2) ^ sw)) = p;
        }
    }

    const f32x16 z16 = {0,0,0,0, 0,0,0,0, 0,0,0,0, 0,0,0,0};
    f32x16 acc0 = z16, acc1 = z16;
    const float* xb = x + (size_t)b * CH * NN + nblk * 128;

    for (int cs = 0; cs < 4; ++cs) {
        if (cs) __syncthreads();
#pragma unroll
        for (int half = 0; half < 2; ++half) {
            const int cl0 = half * 32 + 4 * (t >> 5);
            const int nl0 = 4 * (t & 31);
            const float4 r0 = *reinterpret_cast<const float4*>(xb + (size_t)(cs*64 + cl0 + 0) * NN + nl0);
            const float4 r1 = *reinterpret_cast<const float4*>(xb + (size_t)(cs*64 + cl0 + 1) * NN + nl0);
            const float4 r2 = *reinterpret_cast<const float4*>(xb + (size_t)(cs*64 + cl0 + 2) * NN + nl0);
            const float4 r3 = *reinterpret_cast<const float4*>(xb + (size_t)(cs*64 + cl0 + 3) * NN + nl0);
#pragma unroll
            for (int e = 0; e < 4; ++e) {
                const int nl = nl0 + e;
                u32x2 p;
                p.x = pack2bf(((const float*)&r0)[e], ((const float*)&r1)[e]);
                p.y = pack2bf(((const float*)&r2)[e], ((const float*)&r3)[e]);
                *reinterpret_cast<u32x2*>((char*)Xl + ((nl * 128 + cl0 * 2) ^ swz(nl))) = p;
            }
        }
        __syncthreads();
#pragma unroll
        for (int kl = 0; kl < 4; ++kl) {
            const int ks  = cs * 4 + kl;
            const int chl = 32 * wc + l31;
            const bf16x8 af = *reinterpret_cast<const bf16x8*>(
                (char*)Wl + ((chl * 512 + ks * 32 + h5 * 16) ^ swz(chl)));
            {
                const int nl = 64 * wn + l31;
                const bf16x8 bfv = *reinterpret_cast<const bf16x8*>(
                    (char*)Xl + ((nl * 128 + kl * 32 + h5 * 16) ^ swz(nl)));
                acc0 = __builtin_amdgcn_mfma_f32_32x32x16_bf16(af, bfv, acc0, 0, 0, 0);
            }
            {
                const int nl = 64 * wn + 32 + l31;
                const bf16x8 bfv = *reinterpret_cast<const bf16x8*>(
                    (char*)Xl + ((nl * 128 + kl * 32 + h5 * 16) ^ swz(nl)));
                acc1 = __builtin_amdgcn_mfma_f32_32x32x16_bf16(af, bfv, acc1, 0, 0, 0);
            }
        }
    }

    // ---- epilogue: bias + store in fragment-tiled layouts ----
    const int chbase = chb * 64 + 32 * wc;
    if (chb < 4) {
        ushort* vtb = v + (size_t)b * 8 * 128 * 1024;
#pragma unroll
        for (int nt = 0; nt < 2; ++nt) {
            const f32x16 a = nt ? acc1 : acc0;
            const int key = nblk * 128 + 64 * wn + 32 * nt + l31;
            const size_t kb2 = (size_t)(key >> 5) * 1024
                             + ((key >> 4) & 1) * 512 + ((key >> 3) & 1) * 256 + (key & 7);
#pragma unroll
            for (int r = 0; r < 16; ++r) {
                const int ch = chbase + (r & 3) + 8 * (r >> 2) + 4 * h5;
                vtb[(size_t)(ch >> 5) * 128 * 1024 + kb2 + (ch & 31) * 8] = f2bf(a[r] + bv[ch]);
            }
        }
    } else {
        ushort* dst = (wc == 0 ? qT : kT) + (size_t)b * 128 * 1024;
        const float* bs = (wc == 0 ? bq : bk);
        const float bsc = (wc == 0) ? 1.44269504f : 1.0f;
#pragma unroll
        for (int nt = 0; nt < 2; ++nt) {
            const f32x16 a = nt ? acc1 : acc0;
            const int n = nblk * 128 + 64 * wn + 32 * nt + l31;
            uint* tb = (uint*)(dst + (size_t)(n >> 5) * 1024);
#pragma unroll
            for (int r = 0; r < 16; r += 2) {
                const int row = (r & 3) + 8 * (r >> 2) + 4 * h5;   // even
                tb[((row >> 4) & 1) * 256 + ((row >> 3) & 1) * 128 + (n & 31) * 4 + ((row & 7) >> 1)] =
                    pack2bf(a[r] + bs[row] * bsc, a[r + 1] + bs[row + 1] * bsc);
            }
        }
    }
}

// ---------------------------------------------------------------------------
// Flash attention v10 = v9 with the pipeline actually engaged:
//  (1) K loads issued at body END (older than the newest DMA batch) so the
//      steady-state wait is vmcnt(8) retiring exactly V(it)+K(it+1), never 0.
//  (2) V fragment reads are inline-asm ds_read_b128 on raw LDS offsets +
//      explicit lgkmcnt(0) + sched_barrier(0), so the compiler cannot insert
//      a protective vmcnt(0) before them.
// Wave (kg,cg) owns keys 1024*kg..+1024 x channels 128*cg..+128; P stays in
// registers (swapped QK^T + cvt_pk + permlane32_swap, 1-deep p pipeline);
// end-of-kernel kg tree-reduction through aliased LDS.
// ---------------------------------------------------------------------------
__global__ __attribute__((amdgpu_flat_work_group_size(512, 512), amdgpu_waves_per_eu(2, 2)))
void attn_v10(
    const ushort* __restrict__ qT, const ushort* __restrict__ kT,
    const ushort* __restrict__ v, float* __restrict__ out)
{
    const int bid  = blockIdx.x;
    const int xcd  = bid & 7;
    const int b    = xcd >> 1;                       // batch locked to XCD pair
    const int qblk = (bid >> 3) + 32 * (xcd & 1);
    const int i0   = qblk * 64;

    const int t    = threadIdx.x;
    const int w    = t >> 6;
    const int kg   = w >> 1;          // key group 0..3 (1024 keys each)
    const int cg   = w & 1;           // channel half 0..1 (128 ch each)
    const int lane = t & 63;
    const int l31  = lane & 31;
    const int h5   = lane >> 5;
    const int lo8  = lane * 8;        // frag lane offset (ushort units)

    __shared__ alignas(16) char ldsA[131072];   // main loop: 8 waves x 16 KB V dbuf
                                                // epilogue: f32x4 cbuf (aliased)
    __shared__ float red[2][4][32];             // 1 KB denominators [qt][kg][q]

    char* wb = ldsA + w * 16384;      // this wave's stage region

    // wave-uniform bases (lane offset added only at deref)
    const ushort* qTu = qT + (size_t)b * 128 * 1024;
    const ushort* kTu = kT + ((size_t)b * 128 + kg * 32) * 1024;
    const ushort* vfu = v + (((size_t)b * 8 + cg * 4) * 128 + kg * 32) * 1024;

    // Q B-frags (col = query), both halves, contraction 32 in 2 ksteps
    bf16x8 qf[2][2];
#pragma unroll
    for (int qt = 0; qt < 2; ++qt)
#pragma unroll
        for (int ks = 0; ks < 2; ++ks)
            qf[qt][ks] = *reinterpret_cast<const bf16x8*>(
                qTu + (size_t)((i0 >> 5) + qt) * 1024 + ks * 512 + lo8);

    const f32x16 z16 = {0,0,0,0, 0,0,0,0, 0,0,0,0, 0,0,0,0};
    f32x16 acc[4][2];
#pragma unroll
    for (int ct = 0; ct < 4; ++ct) { acc[ct][0] = z16; acc[ct][1] = z16; }
    float ts0 = 0.f, ts1 = 0.f;

    auto expack = [&](const f32x16& s, float& ts, bf16x8& b0, bf16x8& b1) {
        float p[16];
#pragma unroll
        for (int r = 0; r < 16; ++r) p[r] = __builtin_exp2f(s[r]);
        ts += (((p[0]+p[1])+(p[2]+p[3])) + ((p[4]+p[5])+(p[6]+p[7])))
            + (((p[8]+p[9])+(p[10]+p[11])) + ((p[12]+p[13])+(p[14]+p[15])));
        const uint pk0 = cvt_pk_bf16(p[0],  p[1]);
        const uint pk1 = cvt_pk_bf16(p[2],  p[3]);
        const uint pk2 = cvt_pk_bf16(p[4],  p[5]);
        const uint pk3 = cvt_pk_bf16(p[6],  p[7]);
        const uint pk4 = cvt_pk_bf16(p[8],  p[9]);
        const uint pk5 = cvt_pk_bf16(p[10], p[11]);
        const uint pk6 = cvt_pk_bf16(p[12], p[13]);
        const uint pk7 = cvt_pk_bf16(p[14], p[15]);
        const u32x2 s02 = __builtin_amdgcn_permlane32_swap(pk0, pk2, false, false);
        const u32x2 s13 = __builtin_amdgcn_permlane32_swap(pk1, pk3, false, false);
        const u32x2 s46 = __builtin_amdgcn_permlane32_swap(pk4, pk6, false, false);
        const u32x2 s57 = __builtin_amdgcn_permlane32_swap(pk5, pk7, false, false);
        UB u0; u0.u = u32x4{ s02.x, s13.x, s02.y, s13.y };   // keys 8h5..+7   (ks0)
        UB u1; u1.u = u32x4{ s46.x, s57.x, s46.y, s57.y };   // keys 16+8h5..+7 (ks1)
        b0 = u0.h; b1 = u1.h;
    };

    // ---- prologue: stage V(0) DMA, K(0) -> S(0) -> p(0), then issue K(1) ----
#pragma unroll
    for (int j = 0; j < 8; ++j)
        gll16(vfu + (size_t)(j >> 1) * 131072 + (j & 1) * 512 + lo8, wb + j * 1024);

    bf16x8 kf0 = *reinterpret_cast<const bf16x8*>(kTu + lo8);
    bf16x8 kf1 = *reinterpret_cast<const bf16x8*>(kTu + 512 + lo8);

    bf16x8 p00, p01, p10, p11;
    {   // compiler inserts vmcnt(0) for kf here (drains V(0) too — one-time)
        f32x16 s0 = __builtin_amdgcn_mfma_f32_32x32x16_bf16(kf0, qf[0][0], z16, 0, 0, 0);
        s0 = __builtin_amdgcn_mfma_f32_32x32x16_bf16(kf1, qf[0][1], s0, 0, 0, 0);
        expack(s0, ts0, p00, p01);
        f32x16 s1 = __builtin_amdgcn_mfma_f32_32x32x16_bf16(kf0, qf[1][0], z16, 0, 0, 0);
        s1 = __builtin_amdgcn_mfma_f32_32x32x16_bf16(kf1, qf[1][1], s1, 0, 0, 0);
        expack(s1, ts1, p10, p11);
    }
    {   // K(1) for S(1): issued BEFORE body(0)'s V(1) DMA -> stays older
        const ushort* kr = kTu + 1024;
        kf0 = *reinterpret_cast<const bf16x8*>(kr + lo8);
        kf1 = *reinterpret_cast<const bf16x8*>(kr + 512 + lo8);
    }

#pragma unroll 1
    for (int it = 0; it < 32; ++it) {
        char* cur = wb + (it & 1) * 8192;

        if (it != 31) {
            // ---- issue V(it+1) DMA (8 x 1KB, zero VGPR in flight) ----
            char* nxt = wb + ((it + 1) & 1) * 8192;
            const ushort* vsrc = vfu + (size_t)(it + 1) * 1024;
#pragma unroll
            for (int j = 0; j < 8; ++j)
                gll16(vsrc + (size_t)(j >> 1) * 131072 + (j & 1) * 512 + lo8, nxt + j * 1024);
            // retire V(it)+K(it+1) (the 10 oldest); V(it+1) stays in flight
            asm volatile("s_waitcnt vmcnt(8)" ::: "memory");
        } else {
            asm volatile("s_waitcnt vmcnt(0)" ::: "memory");
        }
        __builtin_amdgcn_sched_barrier(0);

        // ---- asm ds_read V(it) frags (invisible to the waitcnt pass) ----
        UB vf[8];
        const uint base = ldsOff(cur) + lane * 16;
#pragma unroll
        for (int j = 0; j < 8; ++j)
            asm volatile("ds_read_b128 %0, %1" : "=v"(vf[j].u) : "v"(base + j * 1024));
        asm volatile("s_waitcnt lgkmcnt(0)" ::: "memory");
        __builtin_amdgcn_sched_barrier(0);

        // ---- PV(it) with p from previous body ----
#pragma unroll
        for (int ct = 0; ct < 4; ++ct) {
            acc[ct][0] = __builtin_amdgcn_mfma_f32_32x32x16_bf16(vf[2*ct].h,   p00, acc[ct][0], 0, 0, 0);
            acc[ct][0] = __builtin_amdgcn_mfma_f32_32x32x16_bf16(vf[2*ct+1].h, p01, acc[ct][0], 0, 0, 0);
            acc[ct][1] = __builtin_amdgcn_mfma_f32_32x32x16_bf16(vf[2*ct].h,   p10, acc[ct][1], 0, 0, 0);
            acc[ct][1] = __builtin_amdgcn_mfma_f32_32x32x16_bf16(vf[2*ct+1].h, p11, acc[ct][1], 0, 0, 0);
        }

        // ---- S(it+1) + expack -> p ----
        if (it != 31) {
            f32x16 s0 = __builtin_amdgcn_mfma_f32_32x32x16_bf16(kf0, qf[0][0], z16, 0, 0, 0);
            s0 = __builtin_amdgcn_mfma_f32_32x32x16_bf16(kf1, qf[0][1], s0, 0, 0, 0);
            expack(s0, ts0, p00, p01);
            f32x16 s1 = __builtin_amdgcn_mfma_f32_32x32x16_bf16(kf0, qf[1][0], z16, 0, 0, 0);
            s1 = __builtin_amdgcn_mfma_f32_32x32x16_bf16(kf1, qf[1][1], s1, 0, 0, 0);
            expack(s1, ts1, p10, p11);
        }
        // ---- issue K(it+2) at body END (older than next body's DMA) ----
        if (it < 30) {
            const ushort* kr = kTu + (size_t)(it + 2) * 1024;
            kf0 = *reinterpret_cast<const bf16x8*>(kr + lo8);
            kf1 = *reinterpret_cast<const bf16x8*>(kr + 512 + lo8);
        }
    }

    // ---- denominators: sum key-halves, publish per-kg partials (cg0 only) ----
    ts0 += __shfl_xor(ts0, 32);
    ts1 += __shfl_xor(ts1, 32);
    if (cg == 0 && lane < 32) { red[0][kg][l31] = ts0; red[1][kg][l31] = ts1; }

    // ---- kg tree-reduction of acc through LDS (stage region now dead) ----
    f32x4* cb = reinterpret_cast<f32x4*>(ldsA);   // [pair][cg][ct][qt][rg][lane]
    auto cidx = [&](int pair, int ct, int qt, int rg) {
        return ((((pair * 2 + cg) * 4 + ct) * 2 + qt) * 4 + rg) * 64 + lane;
    };
    auto writeC = [&](int pair) {
#pragma unroll
        for (int ct = 0; ct < 4; ++ct)
#pragma unroll
            for (int qt = 0; qt < 2; ++qt)
#pragma unroll
                for (int rg = 0; rg < 4; ++rg) {
                    f32x4 vv = { acc[ct][qt][4*rg],   acc[ct][qt][4*rg+1],
                                 acc[ct][qt][4*rg+2], acc[ct][qt][4*rg+3] };
                    cb[cidx(pair, ct, qt, rg)] = vv;
                }
    };
    auto addC = [&](int pair) {
#pragma unroll
        for (int ct = 0; ct < 4; ++ct)
#pragma unroll
            for (int qt = 0; qt < 2; ++qt)
#pragma unroll
                for (int rg = 0; rg < 4; ++rg) {
                    const f32x4 vv = cb[cidx(pair, ct, qt, rg)];
                    acc[ct][qt][4*rg]   += vv.x;
                    acc[ct][qt][4*rg+1] += vv.y;
                    acc[ct][qt][4*rg+2] += vv.z;
                    acc[ct][qt][4*rg+3] += vv.w;
                }
    };

    __syncthreads();   // stage buffers dead everywhere before aliasing as cbuf
    if (kg >= 2) writeC(kg - 2);
    __syncthreads();
    if (kg < 2) addC(kg);
    __syncthreads();
    if (kg == 1) writeC(1);
    __syncthreads();
    if (kg == 0) {
        addC(1);
        const float inv0 = 1.0f / (red[0][0][l31] + red[0][1][l31] + red[0][2][l31] + red[0][3][l31]);
        const float inv1 = 1.0f / (red[1][0][l31] + red[1][1][l31] + red[1][2][l31] + red[1][3][l31]);
        float* ob = out + (size_t)b * CH * NN + i0;
#pragma unroll
        for (int ct = 0; ct < 4; ++ct)
#pragma unroll
            for (int qt = 0; qt < 2; ++qt) {
                const float inv = qt ? inv1 : inv0;
#pragma unroll
                for (int r = 0; r < 16; ++r) {
                    const int chl = 128 * cg + 32 * ct + (r & 3) + 8 * (r >> 2) + 4 * h5;
                    ob[(size_t)chl * NN + 32 * qt + l31] = acc[ct][qt][r] * inv;
                }
            }
    }
}

extern "C" void kernel_launch(void* const* d_in, const int* in_sizes, int n_in,
                              void* d_out, int out_size, void* d_ws, size_t ws_size,
                              hipStream_t stream) {
    const float* x  = (const float*)d_in[0];
    const float* Wq = (const float*)d_in[1];
    const float* bq = (const float*)d_in[2];
    const float* Wk = (const float*)d_in[3];
    const float* bk = (const float*)d_in[4];
    const float* Wv = (const float*)d_in[5];
    const float* bv = (const float*)d_in[6];
    float* out = (float*)d_out;

    ushort* ws = (ushort*)d_ws;
    ushort* qTf = ws;                                   // 4*128 tiles * 2KB = 1 MB
    ushort* kTf = qTf + (size_t)4 * 128 * 1024;         // 1 MB
    ushort* vf  = kTf + (size_t)4 * 128 * 1024;         // 4*8*128 tiles * 2KB = 8 MB

    proj_mfma<<<dim3(32, 5, 4), 256, 0, stream>>>(x, Wq, bq, Wk, bk, Wv, bv, qTf, kTf, vf);
    attn_v10<<<dim3(256), 512, 0, stream>>>(qTf, kTf, vf, out);
}